// Round 13
// baseline (794.698 us; speedup 1.0000x reference)
//
#include <hip/hip_runtime.h>
#include <math.h>

#define N_NODES 100000
#define N_EDGES 1600000
#define D 128
#define NBKT 391   // ceil(N_NODES/256) buckets of 256 dst nodes

typedef __attribute__((ext_vector_type(8))) short short8;
typedef __attribute__((ext_vector_type(4))) float floatx4;

__device__ __forceinline__ float bf2f(unsigned short u) {
    union { unsigned int i; float f; } v;
    v.i = ((unsigned int)u) << 16;
    return v.f;
}
__device__ __forceinline__ unsigned short f2bf(float f) {
    union { float f; unsigned int i; } v;
    v.f = f;
    unsigned int u = v.i;
    u += 0x7fffu + ((u >> 16) & 1u);
    return (unsigned short)(u >> 16);
}
__device__ __forceinline__ unsigned short f2h(float f) {
    union { _Float16 h; unsigned short u; } c;
    c.h = (_Float16)f;
    return c.u;
}
__device__ __forceinline__ float h2f(unsigned short u) {
    union { unsigned short u; _Float16 h; } c;
    c.u = u;
    return (float)c.h;
}

// split 8 consecutive fp32 into hi/lo bf16 fragments (RNE) — in-register, R3/R8-proven
__device__ __forceinline__ void split8(const float* p, short8& hi, short8& lo) {
    float4 v0 = *(const float4*)p;
    float4 v1 = *(const float4*)(p + 4);
    float f[8] = {v0.x, v0.y, v0.z, v0.w, v1.x, v1.y, v1.z, v1.w};
#pragma unroll
    for (int i = 0; i < 8; ++i) {
        unsigned short h = f2bf(f[i]);
        hi[i] = (short)h;
        lo[i] = (short)f2bf(f[i] - bf2f(h));
    }
}

// same but source is 8 fp16 values (cvt to fp32 in-register first) — R9-validated consumer pattern
__device__ __forceinline__ void split8h(const unsigned short* __restrict__ p, short8& hi, short8& lo) {
    uint4 v = *(const uint4*)p;
    unsigned int uu[4] = {v.x, v.y, v.z, v.w};
    float f[8];
#pragma unroll
    for (int i = 0; i < 4; ++i) {
        f[2 * i]     = h2f((unsigned short)(uu[i] & 0xffffu));
        f[2 * i + 1] = h2f((unsigned short)(uu[i] >> 16));
    }
#pragma unroll
    for (int i = 0; i < 8; ++i) {
        unsigned short h = f2bf(f[i]);
        hi[i] = (short)h;
        lo[i] = (short)f2bf(f[i] - bf2f(h));
    }
}

// stage ONE 32KB weight array into LDS, fragment-major:
// entry e = (ct*4+ks)*64 + lane  holds  W[ct*16+(lane&15)][ks*32+(lane>>4)*8 .. +8]
__device__ __forceinline__ void stage1(unsigned short* sW,
                                       const unsigned short* __restrict__ W, int tid) {
#pragma unroll
    for (int i = 0; i < 8; ++i) {
        int e = tid + 256 * i;
        int ct = e >> 8;
        int ks = (e >> 6) & 3;
        int q = (e >> 4) & 3;
        int l = e & 15;
        size_t g = (size_t)(ct * 16 + l) * D + ks * 32 + q * 8;
        *(uint4*)(sW + (size_t)e * 8) = *(const uint4*)(W + g);
    }
}

// ---------------- weights: fp32 -> (hi,lo) bf16 RNE split ----------------
__global__ void k_cvt_split(const float* __restrict__ s, unsigned short* __restrict__ hi,
                            unsigned short* __restrict__ lo, int n4) {
    int i = blockIdx.x * 256 + threadIdx.x;
    if (i < n4) {
        float4 v = ((const float4*)s)[i];
        float f[4] = {v.x, v.y, v.z, v.w};
        ushort4 h, l;
        unsigned short* hp = (unsigned short*)&h;
        unsigned short* lp = (unsigned short*)&l;
#pragma unroll
        for (int c = 0; c < 4; ++c) {
            unsigned short hh = f2bf(f[c]);
            hp[c] = hh;
            lp[c] = f2bf(f[c] - bf2f(hh));
        }
        ((ushort4*)hi)[i] = h;
        ((ushort4*)lo)[i] = l;
    }
}

// ---------------- x: fp32 -> fp16 ----------------
__global__ void k_cvt_f16(const float* __restrict__ s, unsigned short* __restrict__ d, int n4) {
    int i = blockIdx.x * 256 + threadIdx.x;
    if (i < n4) {
        float4 v = ((const float4*)s)[i];
        ushort4 o;
        o.x = f2h(v.x); o.y = f2h(v.y); o.z = f2h(v.z); o.w = f2h(v.w);
        ((ushort4*)d)[i] = o;
    }
}

// ---------------- CSR build (R11-proven bucketed) ----------------
__global__ void k_hist(const int* __restrict__ dst, int* __restrict__ deg) {
    int e = blockIdx.x * 256 + threadIdx.x;
    if (e < N_EDGES) atomicAdd(&deg[dst[e]], 1);
}

__global__ void k_scan1(const int* __restrict__ deg, int* __restrict__ offs,
                        int* __restrict__ bsums) {
    __shared__ int tmp[256];
    int tid = threadIdx.x;
    int i = blockIdx.x * 256 + tid;
    int v = (i < N_NODES) ? deg[i] : 0;
    tmp[tid] = v;
    __syncthreads();
    for (int off = 1; off < 256; off <<= 1) {
        int t = (tid >= off) ? tmp[tid - off] : 0;
        __syncthreads();
        if (tid >= off) tmp[tid] += t;
        __syncthreads();
    }
    if (i < N_NODES) offs[i] = tmp[tid] - v;
    if (tid == 255) bsums[blockIdx.x] = tmp[255];
}

__global__ void k_scan2(int* __restrict__ bsums, int nb) {
    __shared__ int tmp[512];
    int tid = threadIdx.x;
    int v = (tid < nb) ? bsums[tid] : 0;
    tmp[tid] = v;
    __syncthreads();
    for (int off = 1; off < 512; off <<= 1) {
        int t = (tid >= off) ? tmp[tid - off] : 0;
        __syncthreads();
        if (tid >= off) tmp[tid] += t;
        __syncthreads();
    }
    if (tid < nb) bsums[tid] = tmp[tid] - v;
}

__global__ void k_scan3(const int* __restrict__ deg, int* __restrict__ offs,
                        const int* __restrict__ bsums, int* __restrict__ cursor,
                        float* __restrict__ inv_deg) {
    int i = blockIdx.x * 256 + threadIdx.x;
    if (i < N_NODES) {
        int o = offs[i] + bsums[blockIdx.x];
        offs[i] = o;
        cursor[i] = o;
        int d = deg[i];
        inv_deg[i] = 1.0f / (float)(d > 1 ? d : 1);
        if (i == 0) offs[N_NODES] = N_EDGES;
    }
}

__global__ void k_binit(const int* __restrict__ offs, int* __restrict__ bcur) {
    int b = blockIdx.x * 256 + threadIdx.x;
    if (b < NBKT) bcur[b] = offs[b << 8];
}

__global__ __launch_bounds__(256) void k_bucket(const int* __restrict__ src,
                                                const int* __restrict__ dst,
                                                int* __restrict__ bcur, uint2* __restrict__ pairs) {
    __shared__ int cnt[NBKT];
    __shared__ int off[NBKT];
    int tid = threadIdx.x;
    for (int i = tid; i < NBKT; i += 256) cnt[i] = 0;
    __syncthreads();
    int e0 = blockIdx.x * 4096;
    int mydst[16], mysrc[16];
#pragma unroll
    for (int i = 0; i < 16; ++i) {
        int e = e0 + tid + i * 256;
        int d = (e < N_EDGES) ? dst[e] : -1;
        mydst[i] = d;
        mysrc[i] = (e < N_EDGES) ? src[e] : 0;
        if (d >= 0) atomicAdd(&cnt[d >> 8], 1);
    }
    __syncthreads();
    for (int b = tid; b < NBKT; b += 256) {
        int c = cnt[b];
        off[b] = c ? atomicAdd(&bcur[b], c) : 0;
    }
    __syncthreads();
#pragma unroll
    for (int i = 0; i < 16; ++i) {
        int d = mydst[i];
        if (d >= 0) {
            int p = atomicAdd(&off[d >> 8], 1);
            pairs[p] = make_uint2((unsigned)mysrc[i], (unsigned)d);
        }
    }
}

__global__ __launch_bounds__(256) void k_fill2(const uint2* __restrict__ pairs,
                                               const int* __restrict__ offs,
                                               int* __restrict__ cursor, int* __restrict__ csr_src) {
    int b = blockIdx.x;
    int beg = offs[b << 8];
    int endn = (b + 1) << 8;
    if (endn > N_NODES) endn = N_NODES;
    int end = offs[endn];
    for (int e = beg + threadIdx.x; e < end; e += 256) {
        uint2 pr = pairs[e];
        int p = atomicAdd(&cursor[pr.y], 1);
        csr_src[p] = (int)pr.x;
    }
}

// ---------------- fused gather + SAGE layer ----------------
// Each block: 64 nodes. Each wave: gathers mean-agg for ITS 16 GEMM rows into
// wave-private LDS, then phase-GEMM with LDS-staged weights (R12 structure).
// MODE 0: hin = x fp32; skip = x@projW^T+projB (fused); writes hf_out
// MODE 1: hin = hf fp16; skip = hf; writes hf_out
// MODE 2: hin = hf fp16; skip = hf; fused head -> outp
template <int MODE>
__global__ __launch_bounds__(256, 2) void k_fused(
    const unsigned short* __restrict__ gf,     // fp16 gather/hin/skip source
    const float* __restrict__ hin32,           // MODE 0 only: x fp32
    const int* __restrict__ offs, const int* __restrict__ csr_src,
    const float* __restrict__ inv_deg,
    const unsigned short* __restrict__ Wlh, const unsigned short* __restrict__ Wll,
    const unsigned short* __restrict__ Wrh, const unsigned short* __restrict__ Wrl,
    const unsigned short* __restrict__ pWh, const unsigned short* __restrict__ pWl,
    const float* __restrict__ projB,
    const float* __restrict__ lb, const float* __restrict__ g,
    const float* __restrict__ beta,
    unsigned short* __restrict__ houtf,
    const float* __restrict__ hw, const float* __restrict__ hb_bias,
    const float* __restrict__ rr, const float* __restrict__ alphap,
    float* __restrict__ outp) {
    __shared__ unsigned short sW[16384];      // 32KB, one weight array at a time
    __shared__ float aggL[4][16][132];        // wave-private agg rows (+4 pad: bank spread)

    int tid = threadIdx.x;
    int w = tid >> 6, lane = tid & 63;
    int quad = lane >> 4, l16 = lane & 15;
    int half = lane >> 5, l32 = lane & 31;
    int base = blockIdx.x * 64 + w * 16;

    // issue phase-1 weight staging early — overlaps the gather below
    stage1(sW, Wlh, tid);

    // gather: half-wave per node, 8 nodes sequential; lane reads uint2 (4 fp16 cols)
    for (int i = 0; i < 8; ++i) {
        int node = base + half * 8 + i;
        float a0 = 0.f, a1 = 0.f, a2 = 0.f, a3 = 0.f;
        if (node < N_NODES) {
            int beg = offs[node], end = offs[node + 1];
            int e = beg;
            for (; e + 7 < end; e += 8) {
                int ss[8];
#pragma unroll
                for (int j = 0; j < 8; ++j) ss[j] = csr_src[e + j];
                uint2 vv[8];
#pragma unroll
                for (int j = 0; j < 8; ++j)
                    vv[j] = ((const uint2*)(gf + (size_t)ss[j] * D))[l32];
#pragma unroll
                for (int j = 0; j < 8; ++j) {
                    a0 += h2f((unsigned short)(vv[j].x & 0xffffu));
                    a1 += h2f((unsigned short)(vv[j].x >> 16));
                    a2 += h2f((unsigned short)(vv[j].y & 0xffffu));
                    a3 += h2f((unsigned short)(vv[j].y >> 16));
                }
            }
            for (; e + 3 < end; e += 4) {
                int ss[4];
#pragma unroll
                for (int j = 0; j < 4; ++j) ss[j] = csr_src[e + j];
                uint2 vv[4];
#pragma unroll
                for (int j = 0; j < 4; ++j)
                    vv[j] = ((const uint2*)(gf + (size_t)ss[j] * D))[l32];
#pragma unroll
                for (int j = 0; j < 4; ++j) {
                    a0 += h2f((unsigned short)(vv[j].x & 0xffffu));
                    a1 += h2f((unsigned short)(vv[j].x >> 16));
                    a2 += h2f((unsigned short)(vv[j].y & 0xffffu));
                    a3 += h2f((unsigned short)(vv[j].y >> 16));
                }
            }
            for (; e < end; ++e) {
                int s = csr_src[e];
                uint2 v = ((const uint2*)(gf + (size_t)s * D))[l32];
                a0 += h2f((unsigned short)(v.x & 0xffffu));
                a1 += h2f((unsigned short)(v.x >> 16));
                a2 += h2f((unsigned short)(v.y & 0xffffu));
                a3 += h2f((unsigned short)(v.y >> 16));
            }
            float id = inv_deg[node];
            a0 *= id; a1 *= id; a2 *= id; a3 *= id;
        }
        *(float4*)&aggL[w][half * 8 + i][l32 * 4] = make_float4(a0, a1, a2, a3);
    }
    __syncthreads();   // sW(Wlh) staged + aggL complete

    int koff = quad * 8;
    floatx4 z = {0.f, 0.f, 0.f, 0.f};
    floatx4 acc[8];
#pragma unroll
    for (int ct = 0; ct < 8; ++ct) acc[ct] = z;

    // A-fragments for agg (from wave-private LDS), reused across Wl hi/lo phases
    short8 ah[4], al[4];
#pragma unroll
    for (int ks = 0; ks < 4; ++ks) split8(&aggL[w][l16][ks * 32 + koff], ah[ks], al[ks]);

    // phase 1: Wl hi  (A_hi·W_hi + A_lo·W_hi)
#pragma unroll
    for (int ks = 0; ks < 4; ++ks)
#pragma unroll
        for (int ct = 0; ct < 8; ++ct) {
            short8 wf = *(const short8*)(sW + ((ct * 4 + ks) * 64 + lane) * 8);
            acc[ct] = __builtin_amdgcn_mfma_f32_16x16x32_bf16(ah[ks], wf, acc[ct], 0, 0, 0);
            acc[ct] = __builtin_amdgcn_mfma_f32_16x16x32_bf16(al[ks], wf, acc[ct], 0, 0, 0);
        }
    __syncthreads();
    stage1(sW, Wll, tid);
    __syncthreads();
    // phase 2: Wl lo  (A_hi·W_lo)
#pragma unroll
    for (int ks = 0; ks < 4; ++ks)
#pragma unroll
        for (int ct = 0; ct < 8; ++ct) {
            short8 wf = *(const short8*)(sW + ((ct * 4 + ks) * 64 + lane) * 8);
            acc[ct] = __builtin_amdgcn_mfma_f32_16x16x32_bf16(ah[ks], wf, acc[ct], 0, 0, 0);
        }
    __syncthreads();
    stage1(sW, Wrh, tid);

    // hin fragments (issued while Wrh stages): MODE 0 from fp32 x, else from fp16 h
    int ar = base + l16; if (ar > N_NODES - 1) ar = N_NODES - 1;
    short8 bh[4], bl[4];
#pragma unroll
    for (int ks = 0; ks < 4; ++ks) {
        if (MODE == 0) split8(hin32 + (size_t)ar * D + ks * 32 + koff, bh[ks], bl[ks]);
        else           split8h(gf + (size_t)ar * D + ks * 32 + koff, bh[ks], bl[ks]);
    }
    __syncthreads();
    // phase 3: Wr hi
#pragma unroll
    for (int ks = 0; ks < 4; ++ks)
#pragma unroll
        for (int ct = 0; ct < 8; ++ct) {
            short8 wf = *(const short8*)(sW + ((ct * 4 + ks) * 64 + lane) * 8);
            acc[ct] = __builtin_amdgcn_mfma_f32_16x16x32_bf16(bh[ks], wf, acc[ct], 0, 0, 0);
            acc[ct] = __builtin_amdgcn_mfma_f32_16x16x32_bf16(bl[ks], wf, acc[ct], 0, 0, 0);
        }
    __syncthreads();
    stage1(sW, Wrl, tid);
    __syncthreads();
    // phase 4: Wr lo
#pragma unroll
    for (int ks = 0; ks < 4; ++ks)
#pragma unroll
        for (int ct = 0; ct < 8; ++ct) {
            short8 wf = *(const short8*)(sW + ((ct * 4 + ks) * 64 + lane) * 8);
            acc[ct] = __builtin_amdgcn_mfma_f32_16x16x32_bf16(bh[ks], wf, acc[ct], 0, 0, 0);
        }

    floatx4 accR[8];
    if (MODE == 0) {
#pragma unroll
        for (int ct = 0; ct < 8; ++ct) accR[ct] = z;
        __syncthreads();
        stage1(sW, pWh, tid);
        __syncthreads();
#pragma unroll
        for (int ks = 0; ks < 4; ++ks)
#pragma unroll
            for (int ct = 0; ct < 8; ++ct) {
                short8 wf = *(const short8*)(sW + ((ct * 4 + ks) * 64 + lane) * 8);
                accR[ct] = __builtin_amdgcn_mfma_f32_16x16x32_bf16(bh[ks], wf, accR[ct], 0, 0, 0);
                accR[ct] = __builtin_amdgcn_mfma_f32_16x16x32_bf16(bl[ks], wf, accR[ct], 0, 0, 0);
            }
        __syncthreads();
        stage1(sW, pWl, tid);
        __syncthreads();
#pragma unroll
        for (int ks = 0; ks < 4; ++ks)
#pragma unroll
            for (int ct = 0; ct < 8; ++ct) {
                short8 wf = *(const short8*)(sW + ((ct * 4 + ks) * 64 + lane) * 8);
                accR[ct] = __builtin_amdgcn_mfma_f32_16x16x32_bf16(bh[ks], wf, accR[ct], 0, 0, 0);
            }
    }

    // bias + relu in-register
    float lbv[8], gv[8], bv[8];
#pragma unroll
    for (int ct = 0; ct < 8; ++ct) {
        int n = ct * 16 + l16;
        lbv[ct] = lb[n];
        gv[ct] = g[n];
        bv[ct] = beta[n];
    }
#pragma unroll
    for (int ct = 0; ct < 8; ++ct)
#pragma unroll
        for (int r = 0; r < 4; ++r)
            acc[ct][r] = fmaxf(acc[ct][r] + lbv[ct], 0.f);

    // LN stats per row, in-register
    float mu[4], rs[4];
#pragma unroll
    for (int r = 0; r < 4; ++r) {
        float s = 0.f, ss = 0.f;
#pragma unroll
        for (int ct = 0; ct < 8; ++ct) {
            float v = acc[ct][r];
            s += v;
            ss += v * v;
        }
#pragma unroll
        for (int m = 1; m < 16; m <<= 1) {
            s += __shfl_xor(s, m, 64);
            ss += __shfl_xor(ss, m, 64);
        }
        float m_ = s * (1.0f / 128.0f);
        float v_ = ss * (1.0f / 128.0f) - m_ * m_;
        mu[r] = m_;
        rs[r] = rsqrtf(v_ + 1e-5f);
    }

    float pbv[8], hwv[8];
    if (MODE == 0) {
#pragma unroll
        for (int ct = 0; ct < 8; ++ct) pbv[ct] = projB[ct * 16 + l16];
    }
    if (MODE == 2) {
#pragma unroll
        for (int ct = 0; ct < 8; ++ct) hwv[ct] = hw[ct * 16 + l16];
    }

    // epilogue
#pragma unroll
    for (int r = 0; r < 4; ++r) {
        int crow = base + quad * 4 + r;
        bool valid = (crow < N_NODES);
        float m_ = mu[r], rs_ = rs[r];
        size_t ro = (size_t)crow * D;
        if (MODE == 2) {
            float s = 0.f;
#pragma unroll
            for (int ct = 0; ct < 8; ++ct) {
                int col = ct * 16 + l16;
                float sk = valid ? h2f(gf[ro + col]) : 0.f;
                float o = (acc[ct][r] - m_) * rs_ * gv[ct] + bv[ct] + sk;
                s += o * hwv[ct];
            }
#pragma unroll
            for (int m = 1; m < 16; m <<= 1) s += __shfl_xor(s, m, 64);
            if (l16 == 0 && valid) {
                float a = 1.0f / (1.0f + expf(-alphap[0]));
                outp[crow] = a * rr[crow] + (1.0f - a) * (s + hb_bias[0]);
            }
        } else {
            if (!valid) continue;
#pragma unroll
            for (int ct = 0; ct < 8; ++ct) {
                int col = ct * 16 + l16;
                float sk = (MODE == 0) ? (accR[ct][r] + pbv[ct]) : h2f(gf[ro + col]);
                float o = (acc[ct][r] - m_) * rs_ * gv[ct] + bv[ct] + sk;
                houtf[ro + col] = f2h(o);
            }
        }
    }
}

// ---------------- launch ----------------
extern "C" void kernel_launch(void* const* d_in, const int* in_sizes, int n_in,
                              void* d_out, int out_size, void* d_ws, size_t ws_size,
                              hipStream_t stream) {
    const float* x     = (const float*)d_in[0];
    const int*   ei    = (const int*)d_in[1];
    const float* rr    = (const float*)d_in[2];
    const float* projW = (const float*)d_in[3];
    const float* projB = (const float*)d_in[4];
    const float* WlAll = (const float*)d_in[5];
    const float* lbAll = (const float*)d_in[6];
    const float* WrAll = (const float*)d_in[7];
    const float* gAll  = (const float*)d_in[8];
    const float* btAll = (const float*)d_in[9];
    const float* hw    = (const float*)d_in[10];
    const float* hbias = (const float*)d_in[11];
    const float* alpha = (const float*)d_in[12];
    float* out = (float*)d_out;

    const size_t ND2 = (size_t)N_NODES * D * 2;
    char* p = (char*)d_ws;
    unsigned short* xf  = (unsigned short*)p; p += ND2;
    unsigned short* hf0 = (unsigned short*)p; p += ND2;
    unsigned short* hf1 = (unsigned short*)p; p += ND2;
    uint2* pairs = (uint2*)p; p += (size_t)N_EDGES * 8;   // dead after k_fill2
    unsigned short* Wlh = (unsigned short*)p; p += (size_t)3 * D * D * 2;
    unsigned short* Wll = (unsigned short*)p; p += (size_t)3 * D * D * 2;
    unsigned short* Wrh = (unsigned short*)p; p += (size_t)3 * D * D * 2;
    unsigned short* Wrl = (unsigned short*)p; p += (size_t)3 * D * D * 2;
    unsigned short* pWh = (unsigned short*)p; p += (size_t)D * D * 2;
    unsigned short* pWl = (unsigned short*)p; p += (size_t)D * D * 2;
    int* deg     = (int*)p; p += (size_t)N_NODES * 4;
    float* invd  = (float*)p; p += (size_t)N_NODES * 4;
    int* offs    = (int*)p; p += (size_t)(N_NODES + 2) * 4;
    int* cursor  = (int*)p; p += (size_t)N_NODES * 4;
    int* csr_src = (int*)p; p += (size_t)N_EDGES * 4;
    int* bsums   = (int*)p; p += 512 * 4;
    int* bcur    = (int*)p; p += 512 * 4;

    const int* src = ei;
    const int* dst = ei + N_EDGES;

    // weight splits (RNE) + x fp16 copy
    k_cvt_split<<<(3 * D * D / 4 + 255) / 256, 256, 0, stream>>>(WlAll, Wlh, Wll, 3 * D * D / 4);
    k_cvt_split<<<(3 * D * D / 4 + 255) / 256, 256, 0, stream>>>(WrAll, Wrh, Wrl, 3 * D * D / 4);
    k_cvt_split<<<(D * D / 4 + 255) / 256, 256, 0, stream>>>(projW, pWh, pWl, D * D / 4);
    k_cvt_f16<<<(N_NODES * D / 4 + 255) / 256, 256, 0, stream>>>(x, xf, N_NODES * D / 4);

    // CSR build: hist -> scan -> bucket scatter -> local fill
    hipMemsetAsync(deg, 0, (size_t)N_NODES * 4, stream);
    k_hist<<<(N_EDGES + 255) / 256, 256, 0, stream>>>(dst, deg);
    int nb = (N_NODES + 255) / 256;
    k_scan1<<<nb, 256, 0, stream>>>(deg, offs, bsums);
    k_scan2<<<1, 512, 0, stream>>>(bsums, nb);
    k_scan3<<<nb, 256, 0, stream>>>(deg, offs, bsums, cursor, invd);
    k_binit<<<2, 256, 0, stream>>>(offs, bcur);
    k_bucket<<<NBKT, 256, 0, stream>>>(src, dst, bcur, pairs);
    k_fill2<<<NBKT, 256, 0, stream>>>(pairs, offs, cursor, csr_src);

    int gl = (N_NODES + 63) / 64;   // 1563

    // layer 0: gather from xf; hin = x fp32; fused residual projection; -> hf0
    k_fused<0><<<gl, 256, 0, stream>>>(xf, x, offs, csr_src, invd,
                                       Wlh, Wll, Wrh, Wrl, pWh, pWl, projB,
                                       lbAll, gAll, btAll, hf0,
                                       nullptr, nullptr, nullptr, nullptr, nullptr);
    // layer 1: gather/hin/skip = hf0; -> hf1
    k_fused<1><<<gl, 256, 0, stream>>>(hf0, nullptr, offs, csr_src, invd,
                                       Wlh + D * D, Wll + D * D, Wrh + D * D, Wrl + D * D,
                                       nullptr, nullptr, nullptr,
                                       lbAll + D, gAll + D, btAll + D, hf1,
                                       nullptr, nullptr, nullptr, nullptr, nullptr);
    // layer 2: gather/hin/skip = hf1; fused head -> out
    k_fused<2><<<gl, 256, 0, stream>>>(hf1, nullptr, offs, csr_src, invd,
                                       Wlh + 2 * D * D, Wll + 2 * D * D,
                                       Wrh + 2 * D * D, Wrl + 2 * D * D,
                                       nullptr, nullptr, nullptr,
                                       lbAll + 2 * D, gAll + 2 * D, btAll + 2 * D, nullptr,
                                       hw, hbias, rr, alpha, out);
}